// Round 1
// baseline (228.783 us; speedup 1.0000x reference)
//
#include <hip/hip_runtime.h>
#include <stdint.h>

// ---------------------------------------------------------------------------
// AttentionBlock: out = hs + (softmax(mask((hs Wq^T+bq)(hs Wk^T+bk)^T /32)) (hs Wv^T+bv)) Wo^T + bo
// B=4, S=2048, D=1024, fp32 in/out. bf16 MFMA compute, fp32 accumulate.
// ---------------------------------------------------------------------------

typedef __attribute__((ext_vector_type(8))) short bf16x8;
typedef __attribute__((ext_vector_type(4))) float f32x4;

typedef __attribute__((address_space(3))) void lds_void_t;
typedef __attribute__((address_space(1))) const void glb_void_t;

__device__ __forceinline__ ushort f2bf(float f) {
  uint32_t u = __float_as_uint(f);
  u += 0x7FFF + ((u >> 16) & 1);   // round-to-nearest-even
  return (ushort)(u >> 16);
}
__device__ __forceinline__ float bf2f(ushort u) {
  return __uint_as_float(((uint32_t)u) << 16);
}

// ---------------------------------------------------------------------------
// Convert fp32 inputs (X, Wq, Wk, Wv, Wo) to bf16 workspace copies.
// Region sizes: X = 8388608, each W = 1048576 floats. Total/4 = 3145728 float4.
// ---------------------------------------------------------------------------
__global__ __launch_bounds__(256) void convert_all(
    const float* __restrict__ X, const float* __restrict__ Wq,
    const float* __restrict__ Wk, const float* __restrict__ Wv,
    const float* __restrict__ Wo,
    ushort* __restrict__ Xb, ushort* __restrict__ Wqb, ushort* __restrict__ Wkb,
    ushort* __restrict__ Wvb, ushort* __restrict__ Wob) {
  int64_t i = (int64_t)blockIdx.x * blockDim.x + threadIdx.x;  // float4 index
  int64_t o4 = i * 4;
  const float* s; ushort* d; int64_t off;
  if (o4 < 8388608)        { s = X;  d = Xb;  off = o4; }
  else if (o4 < 9437184)   { s = Wq; d = Wqb; off = o4 - 8388608; }
  else if (o4 < 10485760)  { s = Wk; d = Wkb; off = o4 - 9437184; }
  else if (o4 < 11534336)  { s = Wv; d = Wvb; off = o4 - 10485760; }
  else                     { s = Wo; d = Wob; off = o4 - 11534336; }
  float4 v = *(const float4*)(s + off);
  ushort4 o;
  o.x = f2bf(v.x); o.y = f2bf(v.y); o.z = f2bf(v.z); o.w = f2bf(v.w);
  *(ushort4*)(d + off) = o;
}

// ---------------------------------------------------------------------------
// GEMM: C[M,N] = A[M,K] * B[N,K]^T   (both row-major bf16, stride lda/ldb)
// 128x128 tile, BK=64, 256 threads (4 waves, each 64x64 = 4x4 frags of 16x16).
// global_load_lds(16B) staging, XOR-swizzled source + swizzled ds_read_b128.
// MODE: 0 = bf16 out + bias[col]
//       1 = bf16 out + bias[row]
//       2 = bf16 out, * scale (no bias)
//       3 = f32  out + bias[col] + resid[row*ldo+col]
// ---------------------------------------------------------------------------
#define BM 128
#define BN 128
#define BKT 64

template <int MODE>
__global__ __launch_bounds__(256) void gemm_bt(
    const ushort* __restrict__ Ag, const ushort* __restrict__ Bg,
    void* __restrict__ Og, const float* __restrict__ bias,
    const float* __restrict__ resid,
    int M, int N, int K, int lda, int ldb, int ldo,
    long long sAz, long long sBz, long long sOz, float scale) {
  __shared__ ushort As[BM * BKT];
  __shared__ ushort Bs[BN * BKT];

  const int z = blockIdx.z;
  const ushort* A = Ag + (int64_t)z * sAz;
  const ushort* B = Bg + (int64_t)z * sBz;

  const int tilesN = N / BN;
  const int tm = blockIdx.x / tilesN;
  const int tn = blockIdx.x % tilesN;
  const int tid = threadIdx.x;
  const int wid = tid >> 6;
  const int lane = tid & 63;
  const int lr = lane & 15;   // fragment row (A) / col (B) / out col
  const int kq = lane >> 4;   // k-quad
  const int wr = (wid >> 1) * 64;
  const int wc = (wid & 1) * 64;

  f32x4 acc[4][4];
#pragma unroll
  for (int m = 0; m < 4; ++m)
#pragma unroll
    for (int n = 0; n < 4; ++n) acc[m][n] = (f32x4){0.f, 0.f, 0.f, 0.f};

  const int64_t abase = (int64_t)tm * BM;
  const int64_t bbase = (int64_t)tn * BN;

  for (int kt = 0; kt < K; kt += BKT) {
    if (kt) __syncthreads();
    // stage A tile: 128 rows x 64 bf16 = 1024 x 16B chunks; 8 chunks/row.
    // LDS linear; source column-chunk XOR-permuted so swizzled reads see
    // bank-spread data (inverse-swz-source pattern, m173/m201).
#pragma unroll
    for (int r = 0; r < 4; ++r) {
      int idx = r * 256 + tid;
      int row = idx >> 3, slot = idx & 7;
      int sslot = slot ^ (row & 7);
      const ushort* ga = A + (abase + row) * lda + kt + sslot * 8;
      ushort* la = &As[(r * 256 + wid * 64) * 8];
      __builtin_amdgcn_global_load_lds((glb_void_t*)ga, (lds_void_t*)la, 16, 0, 0);
    }
#pragma unroll
    for (int r = 0; r < 4; ++r) {
      int idx = r * 256 + tid;
      int row = idx >> 3, slot = idx & 7;
      int sslot = slot ^ (row & 7);
      const ushort* gb = B + (bbase + row) * ldb + kt + sslot * 8;
      ushort* lb = &Bs[(r * 256 + wid * 64) * 8];
      __builtin_amdgcn_global_load_lds((glb_void_t*)gb, (lds_void_t*)lb, 16, 0, 0);
    }
    __syncthreads();

#pragma unroll
    for (int kk = 0; kk < 2; ++kk) {
      bf16x8 af[4], bfr[4];
#pragma unroll
      for (int m = 0; m < 4; ++m) {
        int row = wr + m * 16 + lr;
        int slot = (kk * 4 + kq) ^ (row & 7);
        af[m] = *(const bf16x8*)&As[row * 64 + slot * 8];
      }
#pragma unroll
      for (int n = 0; n < 4; ++n) {
        int col = wc + n * 16 + lr;
        int slot = (kk * 4 + kq) ^ (col & 7);
        bfr[n] = *(const bf16x8*)&Bs[col * 64 + slot * 8];
      }
#pragma unroll
      for (int m = 0; m < 4; ++m)
#pragma unroll
        for (int n = 0; n < 4; ++n)
          acc[m][n] = __builtin_amdgcn_mfma_f32_16x16x32_bf16(af[m], bfr[n], acc[m][n], 0, 0, 0);
    }
  }

  // Epilogue. C/D frag layout (m89): col = lane&15, row = (lane>>4)*4 + reg.
#pragma unroll
  for (int m = 0; m < 4; ++m) {
#pragma unroll
    for (int n = 0; n < 4; ++n) {
      int c = tn * BN + wc + n * 16 + lr;
      int r0 = tm * BM + wr + m * 16 + kq * 4;
#pragma unroll
      for (int i = 0; i < 4; ++i) {
        int rrow = r0 + i;
        float v = acc[m][n][i];
        int64_t oo = (int64_t)z * sOz + (int64_t)rrow * ldo + c;
        if constexpr (MODE == 0) {
          v += bias[c];
          ((ushort*)Og)[oo] = f2bf(v);
        } else if constexpr (MODE == 1) {
          v += bias[rrow];
          ((ushort*)Og)[oo] = f2bf(v);
        } else if constexpr (MODE == 2) {
          v *= scale;
          ((ushort*)Og)[oo] = f2bf(v);
        } else {
          v += bias[c] + resid[(int64_t)rrow * ldo + c];
          ((float*)Og)[oo] = v;
        }
      }
    }
  }
}

// ---------------------------------------------------------------------------
// Row softmax with key-padding mask, in place on bf16 P[8192][2048].
// Scores were already scaled by 1/sqrt(D) in the GEMM epilogue.
// One block per row, 256 threads, 8 elems/thread.
// ---------------------------------------------------------------------------
__global__ __launch_bounds__(256) void softmax_rows(ushort* __restrict__ P,
                                                    const int* __restrict__ mask) {
  const int row = blockIdx.x;       // 0..8191  (b*2048 + q)
  const int b = row >> 11;
  ushort* prow = P + (int64_t)row * 2048;
  const int* mrow = mask + (b << 11);
  const int tid = threadIdx.x;
  const int wid = tid >> 6, lane = tid & 63;

  float v[8];
#pragma unroll
  for (int t = 0; t < 2; ++t) {
    int c4 = t * 256 + tid;  // ushort4 index, 512 per row
    ushort4 pv = *(const ushort4*)(prow + c4 * 4);
    int4 mv = *(const int4*)(mrow + c4 * 4);
    v[t * 4 + 0] = mv.x ? bf2f(pv.x) : -1e10f;
    v[t * 4 + 1] = mv.y ? bf2f(pv.y) : -1e10f;
    v[t * 4 + 2] = mv.z ? bf2f(pv.z) : -1e10f;
    v[t * 4 + 3] = mv.w ? bf2f(pv.w) : -1e10f;
  }
  float mx = -3e38f;
#pragma unroll
  for (int j = 0; j < 8; ++j) mx = fmaxf(mx, v[j]);
#pragma unroll
  for (int off = 32; off; off >>= 1) mx = fmaxf(mx, __shfl_xor(mx, off));
  __shared__ float redm[4];
  __shared__ float reds[4];
  if (lane == 0) redm[wid] = mx;
  __syncthreads();
  mx = fmaxf(fmaxf(redm[0], redm[1]), fmaxf(redm[2], redm[3]));

  float e[8];
  float s = 0.f;
#pragma unroll
  for (int j = 0; j < 8; ++j) {
    e[j] = __expf(v[j] - mx);
    s += e[j];
  }
#pragma unroll
  for (int off = 32; off; off >>= 1) s += __shfl_xor(s, off);
  if (lane == 0) reds[wid] = s;
  __syncthreads();
  s = reds[0] + reds[1] + reds[2] + reds[3];
  float inv = 1.0f / s;

#pragma unroll
  for (int t = 0; t < 2; ++t) {
    int c4 = t * 256 + tid;
    ushort4 o;
    o.x = f2bf(e[t * 4 + 0] * inv);
    o.y = f2bf(e[t * 4 + 1] * inv);
    o.z = f2bf(e[t * 4 + 2] * inv);
    o.w = f2bf(e[t * 4 + 3] * inv);
    *(ushort4*)(prow + c4 * 4) = o;
  }
}

// ---------------------------------------------------------------------------
// Host-side launch
// ---------------------------------------------------------------------------
extern "C" void kernel_launch(void* const* d_in, const int* in_sizes, int n_in,
                              void* d_out, int out_size, void* d_ws, size_t ws_size,
                              hipStream_t stream) {
  const float* hs = (const float*)d_in[0];
  const int* mask = (const int*)d_in[1];
  const float* Wq = (const float*)d_in[2];
  const float* bq = (const float*)d_in[3];
  const float* Wk = (const float*)d_in[4];
  const float* bk = (const float*)d_in[5];
  const float* Wv = (const float*)d_in[6];
  const float* bv = (const float*)d_in[7];
  const float* Wo = (const float*)d_in[8];
  const float* bo = (const float*)d_in[9];
  float* out = (float*)d_out;
  char* w = (char*)d_ws;

  // Workspace layout (bytes), total 120 MiB:
  ushort* Xb  = (ushort*)(w + 0);          // [8192][1024] bf16
  ushort* Wqb = (ushort*)(w + 16777216);   // [1024][1024]
  ushort* Wkb = (ushort*)(w + 18874368);
  ushort* Wvb = (ushort*)(w + 20971520);
  ushort* Wob = (ushort*)(w + 23068672);
  ushort* Qb  = (ushort*)(w + 25165824);   // [4][2048][1024]
  ushort* Kb  = (ushort*)(w + 41943040);   // [4][2048][1024]
  ushort* Vt  = (ushort*)(w + 58720256);   // [1024][8192]  (V^T, batches in cols)
  ushort* P   = (ushort*)(w + 75497472);   // [4][2048][2048]
  ushort* AO  = (ushort*)(w + 109051904);  // [4][2048][1024]

  // 1. fp32 -> bf16 packing
  convert_all<<<12288, 256, 0, stream>>>(hs, Wq, Wk, Wv, Wo, Xb, Wqb, Wkb, Wvb, Wob);

  // 2. Q = X Wq^T + bq   (M=8192, N=1024, K=1024)
  gemm_bt<0><<<dim3(512, 1, 1), 256, 0, stream>>>(Xb, Wqb, Qb, bq, nullptr,
      8192, 1024, 1024, 1024, 1024, 1024, 0, 0, 0, 1.f);
  // 3. K = X Wk^T + bk
  gemm_bt<0><<<dim3(512, 1, 1), 256, 0, stream>>>(Xb, Wkb, Kb, bk, nullptr,
      8192, 1024, 1024, 1024, 1024, 1024, 0, 0, 0, 1.f);
  // 4. V^T = Wv X^T + bv  (M=1024 rows=e, N=8192 cols=b*2048+s, row bias)
  gemm_bt<1><<<dim3(512, 1, 1), 256, 0, stream>>>(Wvb, Xb, Vt, bv, nullptr,
      1024, 8192, 1024, 1024, 1024, 8192, 0, 0, 0, 1.f);

  // 5. P = (Q K^T) / sqrt(D)  per batch  (M=N=2048, K=1024), bf16 out
  gemm_bt<2><<<dim3(256, 1, 4), 256, 0, stream>>>(Qb, Kb, P, nullptr, nullptr,
      2048, 2048, 1024, 1024, 1024, 2048,
      (long long)2048 * 1024, (long long)2048 * 1024, (long long)2048 * 2048,
      0.03125f);

  // 6. masked softmax rows, in place on P
  softmax_rows<<<8192, 256, 0, stream>>>(P, mask);

  // 7. AO = P V  per batch (M=2048, N=1024, K=2048); B = Vt (ldb=8192, batch cols)
  gemm_bt<2><<<dim3(128, 1, 4), 256, 0, stream>>>(P, Vt, AO, nullptr, nullptr,
      2048, 1024, 2048, 2048, 8192, 1024,
      (long long)2048 * 2048, (long long)2048, (long long)2048 * 1024, 1.f);

  // 8. out = AO Wo^T + bo + hs  (fp32 out)
  gemm_bt<3><<<dim3(512, 1, 1), 256, 0, stream>>>(AO, Wob, (void*)out, bo, hs,
      8192, 1024, 1024, 1024, 1024, 1024, 0, 0, 0, 1.f);
}

// Round 2
// 215.915 us; speedup vs baseline: 1.0596x; 1.0596x over previous
//
#include <hip/hip_runtime.h>
#include <stdint.h>

// ---------------------------------------------------------------------------
// AttentionBlock: out = hs + (softmax(mask((hs Wq^T+bq)(hs Wk^T+bk)^T /32)) (hs Wv^T+bv)) Wo^T + bo
// B=4, S=2048, D=1024, fp32 in/out. bf16 MFMA compute, fp32 accumulate.
// GEMM: 256x128 tile, BK=64, 8 waves, 8-phase pipelined schedule with counted
// vmcnt (T2+T3+T4+T5 per the CDNA4 guide).
// ---------------------------------------------------------------------------

typedef __attribute__((ext_vector_type(8))) short bf16x8;
typedef __attribute__((ext_vector_type(4))) float f32x4;

typedef __attribute__((address_space(3))) void lds_void_t;
typedef __attribute__((address_space(1))) const void glb_void_t;

__device__ __forceinline__ ushort f2bf(float f) {
  uint32_t u = __float_as_uint(f);
  u += 0x7FFF + ((u >> 16) & 1);   // round-to-nearest-even
  return (ushort)(u >> 16);
}
__device__ __forceinline__ float bf2f(ushort u) {
  return __uint_as_float(((uint32_t)u) << 16);
}

// ---------------------------------------------------------------------------
// Convert fp32 inputs (X, Wq, Wk, Wv, Wo) to bf16 workspace copies.
// Last block also concatenates bq|bk into bqk (f32).
// ---------------------------------------------------------------------------
__global__ __launch_bounds__(256) void convert_all(
    const float* __restrict__ X, const float* __restrict__ Wq,
    const float* __restrict__ Wk, const float* __restrict__ Wv,
    const float* __restrict__ Wo, const float* __restrict__ bq,
    const float* __restrict__ bk,
    ushort* __restrict__ Xb, ushort* __restrict__ Wqb, ushort* __restrict__ Wkb,
    ushort* __restrict__ Wvb, ushort* __restrict__ Wob,
    float* __restrict__ bqk) {
  if (blockIdx.x >= 12288) {
    // bias concat: 2048 floats
#pragma unroll
    for (int u = 0; u < 2; ++u) {
      int idx4 = threadIdx.x * 2 + u;   // 0..511
      int base = idx4 * 4;
      float4 v = (base < 1024) ? *(const float4*)(bq + base)
                               : *(const float4*)(bk + base - 1024);
      *(float4*)(bqk + base) = v;
    }
    return;
  }
  int64_t i = (int64_t)blockIdx.x * blockDim.x + threadIdx.x;  // float4 index
  int64_t o4 = i * 4;
  const float* s; ushort* d; int64_t off;
  if (o4 < 8388608)        { s = X;  d = Xb;  off = o4; }
  else if (o4 < 9437184)   { s = Wq; d = Wqb; off = o4 - 8388608; }
  else if (o4 < 10485760)  { s = Wk; d = Wkb; off = o4 - 9437184; }
  else if (o4 < 11534336)  { s = Wv; d = Wvb; off = o4 - 10485760; }
  else                     { s = Wo; d = Wob; off = o4 - 11534336; }
  float4 v = *(const float4*)(s + off);
  ushort4 o;
  o.x = f2bf(v.x); o.y = f2bf(v.y); o.z = f2bf(v.z); o.w = f2bf(v.w);
  *(ushort4*)(d + off) = o;
}

// ---------------------------------------------------------------------------
// 8-phase GEMM: C[M,N] = A[M,K] * B[N,K]^T  (row-major bf16, strides lda/ldb)
// BM=256, BN=128, BK=64. 512 threads = 8 waves as 4(M)x2(N), 64x64 per wave.
// LDS: 2 buffers x (A 32KB + B 16KB) = 96 KB. Chunk-XOR swizzle (T2) via
// pre-swizzled global source + swizzled ds_read (conflict-free, verified r1).
// Schedule: 8 phases / 2 K-tiles per iter; counted vmcnt(2)@ph3, vmcnt(6)@ph7
// (6 loads/thread/K-tile, one tile in flight); setprio around MFMA clusters.
// MODE: 0 = bf16 out + bias[col]
//       1 = bf16 out + bias[row]
//       2 = bf16 out, * scale (no bias)
//       3 = f32  out + bias[col] + resid[row*ldo+col]
// ---------------------------------------------------------------------------

#define BAR   __builtin_amdgcn_s_barrier()
#define SCHED __builtin_amdgcn_sched_barrier(0)
#define LGKM0 asm volatile("s_waitcnt lgkmcnt(0)" ::: "memory")
#define VMC(n) asm volatile("s_waitcnt vmcnt(" #n ")" ::: "memory")

#define ST(gp, loff, BUFBASE)                                                  \
  do {                                                                         \
    __builtin_amdgcn_global_load_lds((glb_void_t*)(gp),                        \
                                     (lds_void_t*)((BUFBASE) + (loff)), 16, 0, 0); \
    (gp) += 64;                                                                \
  } while (0)

template <int MODE>
__global__ __launch_bounds__(512, 2) void gemm8(
    const ushort* __restrict__ Ag, const ushort* __restrict__ Bg,
    void* __restrict__ Og, const float* __restrict__ bias,
    const float* __restrict__ resid,
    int N, int K, int lda, int ldb, int ldo,
    long long sAz, long long sBz, long long sOz, float scale) {
  __shared__ ushort As0[16384], As1[16384], Bs0[8192], Bs1[8192];

  const int z = blockIdx.z;
  const ushort* A = Ag + (int64_t)z * sAz;
  const ushort* B = Bg + (int64_t)z * sBz;

  const int tilesN = N >> 7;
  // bijective XCD-aware swizzle (m204); all our grids have nwg % 8 == 0.
  const int nwg = gridDim.x;
  const int q8 = nwg >> 3, r8 = nwg & 7;
  const int xcd = blockIdx.x & 7, sub = blockIdx.x >> 3;
  const int wg = (xcd < r8 ? xcd * (q8 + 1) : r8 * (q8 + 1) + (xcd - r8) * q8) + sub;
  const int tm = wg / tilesN, tn = wg % tilesN;

  const int tid = threadIdx.x;
  const int wid = tid >> 6;
  const int lane = tid & 63;
  const int lr = lane & 15;   // fragment row (A) / col (B) / out col
  const int kq = lane >> 4;   // k-quad
  const int wr = (wid >> 1) * 64;   // wave row offset within 256
  const int wc = (wid & 1) * 64;    // wave col offset within 128

  // ---- staging addresses: A 4 chunks/thread, B 2 chunks/thread per K-tile
  const int64_t abase = (int64_t)tm * 256;
  const int64_t bbase = (int64_t)tn * 128;

  const int idxA0 = tid, idxA1 = 512 + tid, idxA2 = 1024 + tid, idxA3 = 1536 + tid;
  const int idxB0 = tid, idxB1 = 512 + tid;

  const int rA0 = idxA0 >> 3, rA1 = idxA1 >> 3, rA2 = idxA2 >> 3, rA3 = idxA3 >> 3;
  const int rB0 = idxB0 >> 3, rB1 = idxB1 >> 3;

  const ushort* gA0 = A + (abase + rA0) * lda + ((idxA0 & 7) ^ (rA0 & 7)) * 8;
  const ushort* gA1 = A + (abase + rA1) * lda + ((idxA1 & 7) ^ (rA1 & 7)) * 8;
  const ushort* gA2 = A + (abase + rA2) * lda + ((idxA2 & 7) ^ (rA2 & 7)) * 8;
  const ushort* gA3 = A + (abase + rA3) * lda + ((idxA3 & 7) ^ (rA3 & 7)) * 8;
  const ushort* gB0 = B + (bbase + rB0) * ldb + ((idxB0 & 7) ^ (rB0 & 7)) * 8;
  const ushort* gB1 = B + (bbase + rB1) * ldb + ((idxB1 & 7) ^ (rB1 & 7)) * 8;

  const int lA0 = idxA0 * 8, lA1 = idxA1 * 8, lA2 = idxA2 * 8, lA3 = idxA3 * 8;
  const int lB0 = idxB0 * 8, lB1 = idxB1 * 8;

  // ---- fragment read bases (chunk-swizzled): slot = (ks*4+kq) ^ (lr&7)
  const int rsw0 = (kq ^ (lr & 7)) * 8;
  const int rsw1 = rsw0 ^ 32;            // ((4|kq)^(lr&7))*8
  const ushort* Arp0 = As0 + (wr + lr) * 64;
  const ushort* Arp1 = As1 + (wr + lr) * 64;
  const ushort* Brp0 = Bs0 + (wc + lr) * 64;
  const ushort* Brp1 = Bs1 + (wc + lr) * 64;

  bf16x8 a[4][2], b[4][2];
  f32x4 acc[4][4];
#pragma unroll
  for (int m = 0; m < 4; ++m)
#pragma unroll
    for (int n = 0; n < 4; ++n) acc[m][n] = (f32x4){0.f, 0.f, 0.f, 0.f};

#define RD_A(BUF, mi)                                                    \
  {                                                                      \
    const ushort* p_ = (BUF ? Arp1 : Arp0) + (mi) * 1024;                \
    a[mi][0] = *(const bf16x8*)(p_ + rsw0);                              \
    a[mi][1] = *(const bf16x8*)(p_ + rsw1);                              \
  }
#define RD_B(BUF, ni)                                                    \
  {                                                                      \
    const ushort* p_ = (BUF ? Brp1 : Brp0) + (ni) * 1024;                \
    b[ni][0] = *(const bf16x8*)(p_ + rsw0);                              \
    b[ni][1] = *(const bf16x8*)(p_ + rsw1);                              \
  }
#define MFMA2(mi, ni)                                                                   \
  acc[mi][ni] = __builtin_amdgcn_mfma_f32_16x16x32_bf16(a[mi][0], b[ni][0], acc[mi][ni], 0, 0, 0); \
  acc[mi][ni] = __builtin_amdgcn_mfma_f32_16x16x32_bf16(a[mi][1], b[ni][1], acc[mi][ni], 0, 0, 0);
#define QUAD(m0_, n0_)                                                   \
  __builtin_amdgcn_s_setprio(1);                                         \
  MFMA2(m0_, n0_) MFMA2(m0_, n0_ + 1) MFMA2(m0_ + 1, n0_) MFMA2(m0_ + 1, n0_ + 1) \
  __builtin_amdgcn_s_setprio(0);

  // ---- prologue: stage K-tiles 0 (buf0) and 1 (buf1)
  ST(gA0, lA0, As0); ST(gA1, lA1, As0); ST(gA2, lA2, As0); ST(gA3, lA3, As0);
  ST(gB0, lB0, Bs0); ST(gB1, lB1, Bs0);
  ST(gA0, lA0, As1); ST(gA1, lA1, As1); ST(gA2, lA2, As1); ST(gA3, lA3, As1);
  ST(gB0, lB0, Bs1); ST(gB1, lB1, Bs1);
  VMC(6); BAR; SCHED;

  const int NI = K >> 7;  // two BK=64 tiles per iteration
  for (int i = 0; i < NI; ++i) {
    const bool last = (i == NI - 1);
    // ---- phase 0 (buf0): read A01,B01; MFMA quad(0,0)
    RD_A(0, 0) RD_A(0, 1) RD_B(0, 0) RD_B(0, 1)
    BAR; LGKM0; SCHED;
    QUAD(0, 0)
    SCHED; BAR;
    // ---- phase 1: read B23; quad(0,1)
    RD_B(0, 2) RD_B(0, 3)
    BAR; LGKM0; SCHED;
    QUAD(0, 2)
    SCHED; BAR;
    // ---- phase 2: read A23; quad(1,1)
    RD_A(0, 2) RD_A(0, 3)
    BAR; LGKM0; SCHED;
    QUAD(2, 2)
    SCHED; BAR;
    // ---- phase 3: stage s0.Ahalf0 -> buf0; quad(1,0); vmcnt gate for buf1
    if (!last) { ST(gA0, lA0, As0); ST(gA1, lA1, As0); }
    BAR; SCHED;
    QUAD(2, 0)
    SCHED;
    if (last) { VMC(0); } else { VMC(2); }
    BAR;
    // ---- phase 4 (buf1): read A01,B01; stage s0.Ahalf1; quad(0,0)
    RD_A(1, 0) RD_A(1, 1) RD_B(1, 0) RD_B(1, 1)
    if (!last) { ST(gA2, lA2, As0); ST(gA3, lA3, As0); }
    BAR; LGKM0; SCHED;
    QUAD(0, 0)
    SCHED; BAR;
    // ---- phase 5: read A23,B23; stage s0.B; quad(0,1)
    RD_A(1, 2) RD_A(1, 3) RD_B(1, 2) RD_B(1, 3)
    if (!last) { ST(gB0, lB0, Bs0); ST(gB1, lB1, Bs0); }
    BAR; LGKM0; SCHED;
    QUAD(0, 2)
    SCHED; BAR;
    // ---- phase 6: stage s1.A -> buf1; quad(1,1)
    if (!last) { ST(gA0, lA0, As1); ST(gA1, lA1, As1); ST(gA2, lA2, As1); ST(gA3, lA3, As1); }
    BAR; SCHED;
    QUAD(2, 2)
    SCHED; BAR;
    // ---- phase 7: stage s1.B -> buf1; quad(1,0); vmcnt gate for next buf0
    if (!last) { ST(gB0, lB0, Bs1); ST(gB1, lB1, Bs1); }
    BAR; SCHED;
    QUAD(2, 0)
    SCHED;
    if (!last) { VMC(6); }
    BAR;
  }

  // ---- epilogue. C/D frag layout: col = lane&15, row = (lane>>4)*4 + reg.
#pragma unroll
  for (int m = 0; m < 4; ++m) {
#pragma unroll
    for (int n = 0; n < 4; ++n) {
      int c = tn * 128 + wc + n * 16 + lr;
      int r0 = tm * 256 + wr + m * 16 + kq * 4;
#pragma unroll
      for (int i = 0; i < 4; ++i) {
        int rrow = r0 + i;
        float v = acc[m][n][i];
        int64_t oo = (int64_t)z * sOz + (int64_t)rrow * ldo + c;
        if constexpr (MODE == 0) {
          v += bias[c];
          ((ushort*)Og)[oo] = f2bf(v);
        } else if constexpr (MODE == 1) {
          v += bias[rrow];
          ((ushort*)Og)[oo] = f2bf(v);
        } else if constexpr (MODE == 2) {
          v *= scale;
          ((ushort*)Og)[oo] = f2bf(v);
        } else {
          v += bias[c] + resid[(int64_t)rrow * ldo + c];
          ((float*)Og)[oo] = v;
        }
      }
    }
  }
#undef RD_A
#undef RD_B
#undef MFMA2
#undef QUAD
}

// ---------------------------------------------------------------------------
// Row softmax with key-padding mask, in place on bf16 P[8192][2048].
// ---------------------------------------------------------------------------
__global__ __launch_bounds__(256) void softmax_rows(ushort* __restrict__ P,
                                                    const int* __restrict__ mask) {
  const int row = blockIdx.x;       // 0..8191  (b*2048 + q)
  const int b = row >> 11;
  ushort* prow = P + (int64_t)row * 2048;
  const int* mrow = mask + (b << 11);
  const int tid = threadIdx.x;
  const int wid = tid >> 6, lane = tid & 63;

  float v[8];
#pragma unroll
  for (int t = 0; t < 2; ++t) {
    int c4 = t * 256 + tid;  // ushort4 index, 512 per row
    ushort4 pv = *(const ushort4*)(prow + c4 * 4);
    int4 mv = *(const int4*)(mrow + c4 * 4);
    v[t * 4 + 0] = mv.x ? bf2f(pv.x) : -1e10f;
    v[t * 4 + 1] = mv.y ? bf2f(pv.y) : -1e10f;
    v[t * 4 + 2] = mv.z ? bf2f(pv.z) : -1e10f;
    v[t * 4 + 3] = mv.w ? bf2f(pv.w) : -1e10f;
  }
  float mx = -3e38f;
#pragma unroll
  for (int j = 0; j < 8; ++j) mx = fmaxf(mx, v[j]);
#pragma unroll
  for (int off = 32; off; off >>= 1) mx = fmaxf(mx, __shfl_xor(mx, off));
  __shared__ float redm[4];
  __shared__ float reds[4];
  if (lane == 0) redm[wid] = mx;
  __syncthreads();
  mx = fmaxf(fmaxf(redm[0], redm[1]), fmaxf(redm[2], redm[3]));

  float e[8];
  float s = 0.f;
#pragma unroll
  for (int j = 0; j < 8; ++j) {
    e[j] = __expf(v[j] - mx);
    s += e[j];
  }
#pragma unroll
  for (int off = 32; off; off >>= 1) s += __shfl_xor(s, off);
  if (lane == 0) reds[wid] = s;
  __syncthreads();
  s = reds[0] + reds[1] + reds[2] + reds[3];
  float inv = 1.0f / s;

#pragma unroll
  for (int t = 0; t < 2; ++t) {
    int c4 = t * 256 + tid;
    ushort4 o;
    o.x = f2bf(e[t * 4 + 0] * inv);
    o.y = f2bf(e[t * 4 + 1] * inv);
    o.z = f2bf(e[t * 4 + 2] * inv);
    o.w = f2bf(e[t * 4 + 3] * inv);
    *(ushort4*)(prow + c4 * 4) = o;
  }
}

// ---------------------------------------------------------------------------
// Host-side launch
// ---------------------------------------------------------------------------
extern "C" void kernel_launch(void* const* d_in, const int* in_sizes, int n_in,
                              void* d_out, int out_size, void* d_ws, size_t ws_size,
                              hipStream_t stream) {
  const float* hs = (const float*)d_in[0];
  const int* mask = (const int*)d_in[1];
  const float* Wq = (const float*)d_in[2];
  const float* bq = (const float*)d_in[3];
  const float* Wk = (const float*)d_in[4];
  const float* bk = (const float*)d_in[5];
  const float* Wv = (const float*)d_in[6];
  const float* bv = (const float*)d_in[7];
  const float* Wo = (const float*)d_in[8];
  const float* bo = (const float*)d_in[9];
  float* out = (float*)d_out;
  char* w = (char*)d_ws;

  // Workspace layout (bytes), total 120 MiB:
  ushort* Xb   = (ushort*)(w + 0);          // [8192][1024] bf16
  ushort* Wqb  = (ushort*)(w + 16777216);   // [2048][1024]  (Wq ; Wk adjacent)
  ushort* Wkb  = (ushort*)(w + 18874368);
  ushort* Wvb  = (ushort*)(w + 20971520);
  ushort* Wob  = (ushort*)(w + 23068672);
  ushort* QKb  = (ushort*)(w + 25165824);   // [8192][2048]  (cols 0..1023 Q, 1024.. K)
  ushort* Vt   = (ushort*)(w + 58720256);   // [1024][8192]  (V^T, batches in cols)
  ushort* P    = (ushort*)(w + 75497472);   // [4][2048][2048]
  float*  bqk  = (float*)(w + 75497472);    // 2048 f32, dead before P is written
  ushort* AO   = (ushort*)(w + 109051904);  // [4][2048][1024]

  // 1. fp32 -> bf16 packing (+ bias concat into bqk)
  convert_all<<<12289, 256, 0, stream>>>(hs, Wq, Wk, Wv, Wo, bq, bk,
                                         Xb, Wqb, Wkb, Wvb, Wob, bqk);

  // 2. [Q|K] = X [Wq;Wk]^T + [bq|bk]   (M=8192, N=2048, K=1024)
  gemm8<0><<<dim3(512, 1, 1), 512, 0, stream>>>(Xb, Wqb, QKb, bqk, nullptr,
      2048, 1024, 1024, 1024, 2048, 0, 0, 0, 1.f);

  // 3. V^T = Wv X^T + bv  (M=1024 rows=e, N=8192 cols=token, row bias)
  gemm8<1><<<dim3(256, 1, 1), 512, 0, stream>>>(Wvb, Xb, Vt, bv, nullptr,
      8192, 1024, 1024, 1024, 8192, 0, 0, 0, 1.f);

  // 4. P = (Q K^T) / 32  per batch  (M=N=2048, K=1024), bf16 out
  gemm8<2><<<dim3(128, 1, 4), 512, 0, stream>>>(QKb, QKb + 1024, P, nullptr, nullptr,
      2048, 1024, 2048, 2048, 2048,
      (long long)2048 * 2048, (long long)2048 * 2048, (long long)2048 * 2048,
      0.03125f);

  // 5. masked softmax rows, in place on P
  softmax_rows<<<8192, 256, 0, stream>>>(P, mask);

  // 6. AO = P V  per batch (M=2048, N=1024, K=2048); B = Vt (ldb=8192)
  gemm8<2><<<dim3(64, 1, 4), 512, 0, stream>>>(P, Vt, AO, nullptr, nullptr,
      1024, 2048, 2048, 8192, 1024,
      (long long)2048 * 2048, (long long)2048, (long long)2048 * 1024, 1.f);

  // 7. out = AO Wo^T + bo + hs  (fp32 out)
  gemm8<3><<<dim3(256, 1, 1), 512, 0, stream>>>(AO, Wob, (void*)out, bo, hs,
      1024, 1024, 1024, 1024, 1024, 0, 0, 0, 1.f);
}